// Round 1
// baseline (9118.008 us; speedup 1.0000x reference)
//
#include <hip/hip_runtime.h>
#include <hip/hip_bf16.h>

// MAHGN: 2-layer hetero GAT. fp32 throughout.
// Edge phase uses 3 passes (atomicMax segmax, atomicAdd denom, atomicAdd scatter).

static constexpr int kNUser = 200000;
static constexpr int kNArt  = 100000;
static constexpr int kNCat  = 500;
static constexpr size_t SZ_U = (size_t)kNUser * 64;
static constexpr size_t SZ_A = (size_t)kNArt * 64;
static constexpr size_t SZ_C = (size_t)kNCat * 64;
static constexpr size_t SZ_X = SZ_U + SZ_A + SZ_C;

// monotone float<->int encoding for atomicMax on float
__device__ __forceinline__ int enc_f(float f) {
  int i = __float_as_int(f);
  return i >= 0 ? i : (i ^ 0x7FFFFFFF);
}
__device__ __forceinline__ float dec_f(int i) {
  return __int_as_float(i >= 0 ? i : (i ^ 0x7FFFFFFF));
}

// vd[k][h] = sum_c Wd[k][h*16+c] * att[h][c]   (folds hd computation into a GEMV)
__global__ void k_vd(const float* __restrict__ Wd, const float* __restrict__ att,
                     float* __restrict__ vd) {
  int tid = threadIdx.x;          // 256 = 64 k * 4 h
  int k = tid >> 2, h = tid & 3;
  float s = 0.f;
  #pragma unroll
  for (int c = 0; c < 16; ++c) s += Wd[k * 64 + h * 16 + c] * att[h * 16 + c];
  vd[k * 4 + h] = s;
}

__device__ __forceinline__ void hs_as_write(float acc, float sAv, int tx, int row, int Ns,
                                            float* __restrict__ hs, float* __restrict__ a_s) {
  if (row < Ns) hs[(size_t)row * 64 + tx] = acc;
  // segmented (16-lane) reduction: a_s[row][h] = sum_c hs[row][h*16+c]*att[h][c]
  float t = acc * sAv;
  t += __shfl_xor(t, 8, 64);
  t += __shfl_xor(t, 4, 64);
  t += __shfl_xor(t, 2, 64);
  t += __shfl_xor(t, 1, 64);
  if ((tx & 15) == 0 && row < Ns) a_s[row * 4 + (tx >> 4)] = t;
}

// hs = x @ W  (64x64), plus fused a_s. One wave computes 4 rows at a time.
__global__ __launch_bounds__(256) void k_transform(const float* __restrict__ x,
    const float* __restrict__ W, const float* __restrict__ att,
    float* __restrict__ hs, float* __restrict__ a_s, int Ns)
{
  __shared__ float sW[4096];
  __shared__ float sA[64];
  int tid = threadIdx.x;
  #pragma unroll
  for (int i = 0; i < 16; ++i) sW[tid + 256 * i] = W[tid + 256 * i];
  if (tid < 64) sA[tid] = att[tid];
  __syncthreads();
  int tx = tid & 63, wy = tid >> 6;
  float sAv = sA[tx];
  int base = blockIdx.x * 64 + wy * 16;
  #pragma unroll 1
  for (int it = 0; it < 4; ++it) {
    int r0 = base + it * 4;
    float xv0 = (r0 + 0 < Ns) ? x[(size_t)(r0 + 0) * 64 + tx] : 0.f;
    float xv1 = (r0 + 1 < Ns) ? x[(size_t)(r0 + 1) * 64 + tx] : 0.f;
    float xv2 = (r0 + 2 < Ns) ? x[(size_t)(r0 + 2) * 64 + tx] : 0.f;
    float xv3 = (r0 + 3 < Ns) ? x[(size_t)(r0 + 3) * 64 + tx] : 0.f;
    float a0 = 0.f, a1 = 0.f, a2 = 0.f, a3 = 0.f;
    #pragma unroll
    for (int k = 0; k < 64; ++k) {
      float w = sW[k * 64 + tx];     // 2-way wave64 aliasing on 32 banks: free
      a0 += __shfl(xv0, k, 64) * w;  // constant lane -> v_readlane broadcast
      a1 += __shfl(xv1, k, 64) * w;
      a2 += __shfl(xv2, k, 64) * w;
      a3 += __shfl(xv3, k, 64) * w;
    }
    hs_as_write(a0, sAv, tx, r0 + 0, Ns, hs, a_s);
    hs_as_write(a1, sAv, tx, r0 + 1, Ns, hs, a_s);
    hs_as_write(a2, sAv, tx, r0 + 2, Ns, hs, a_s);
    hs_as_write(a3, sAv, tx, r0 + 3, Ns, hs, a_s);
  }
}

// a_d = x_d @ vd  (64x4 GEMV), thread per dst row
__global__ __launch_bounds__(256) void k_ad(const float* __restrict__ x,
    const float* __restrict__ vd, float* __restrict__ a_d, int Nd)
{
  __shared__ float sV[256];
  int tid = threadIdx.x;
  sV[tid] = vd[tid];
  __syncthreads();
  int n = blockIdx.x * 256 + tid;
  if (n >= Nd) return;
  const float4* x4 = (const float4*)(x + (size_t)n * 64);
  float a0 = 0.f, a1 = 0.f, a2 = 0.f, a3 = 0.f;
  #pragma unroll
  for (int k4 = 0; k4 < 16; ++k4) {
    float4 xv = x4[k4];
    const float* f = &xv.x;
    #pragma unroll
    for (int j = 0; j < 4; ++j) {
      int k = k4 * 4 + j;
      float xk = f[j];
      a0 += xk * sV[k * 4 + 0];
      a1 += xk * sV[k * 4 + 1];
      a2 += xk * sV[k * 4 + 2];
      a3 += xk * sV[k * 4 + 3];
    }
  }
  *(float4*)(a_d + (size_t)n * 4) = make_float4(a0, a1, a2, a3);
}

__global__ void k_init(int* __restrict__ mmax, float* __restrict__ den, int n) {
  int i = blockIdx.x * blockDim.x + threadIdx.x;
  if (i < n) { mmax[i] = (int)0x80000000; den[i] = 0.f; }
}

__global__ __launch_bounds__(256) void k_emax(const int* __restrict__ ei,
    const float* __restrict__ a_s, const float* __restrict__ a_d,
    int* __restrict__ mmax, int E)
{
  int e = blockIdx.x * 256 + threadIdx.x;
  if (e >= E) return;
  int row = ei[e], col = ei[E + e];
  const float4 as = *(const float4*)(a_s + (size_t)row * 4);
  const float4 ad = *(const float4*)(a_d + (size_t)col * 4);
  #pragma unroll
  for (int h = 0; h < 4; ++h) {
    float v = (&as.x)[h] + (&ad.x)[h];
    v = v >= 0.f ? v : 0.2f * v;
    atomicMax(&mmax[(size_t)col * 4 + h], enc_f(v));
  }
}

__global__ __launch_bounds__(256) void k_esum(const int* __restrict__ ei,
    const float* __restrict__ a_s, const float* __restrict__ a_d,
    const int* __restrict__ mmax, float* __restrict__ den, int E)
{
  int e = blockIdx.x * 256 + threadIdx.x;
  if (e >= E) return;
  int row = ei[e], col = ei[E + e];
  const float4 as = *(const float4*)(a_s + (size_t)row * 4);
  const float4 ad = *(const float4*)(a_d + (size_t)col * 4);
  #pragma unroll
  for (int h = 0; h < 4; ++h) {
    float v = (&as.x)[h] + (&ad.x)[h];
    v = v >= 0.f ? v : 0.2f * v;
    float m = dec_f(mmax[(size_t)col * 4 + h]);
    unsafeAtomicAdd(&den[(size_t)col * 4 + h], __expf(v - m));
  }
}

// 64 threads per edge: out[col][d] += hs[row][d] * w[h]
__global__ __launch_bounds__(256) void k_eagg(const int* __restrict__ ei,
    const float* __restrict__ a_s, const float* __restrict__ a_d,
    const int* __restrict__ mmax, const float* __restrict__ den,
    const float* __restrict__ hs, float* __restrict__ out, int E)
{
  long long gid = (long long)blockIdx.x * 256 + threadIdx.x;
  int e = (int)(gid >> 6);
  int d = (int)(gid & 63);
  if (e >= E) return;
  int row = ei[e], col = ei[E + e];
  int h = d >> 4;
  float v = a_s[(size_t)row * 4 + h] + a_d[(size_t)col * 4 + h];
  v = v >= 0.f ? v : 0.2f * v;
  float m = dec_f(mmax[(size_t)col * 4 + h]);
  float w = __expf(v - m) / (den[(size_t)col * 4 + h] + 1e-16f);
  unsafeAtomicAdd(&out[(size_t)col * 64 + d], hs[(size_t)row * 64 + d] * w);
}

// x = leaky_relu(out + sum of biases of edge types targeting this node type, 0.01)
__global__ void k_act(float* __restrict__ x, const float* __restrict__ b0,
                      const float* __restrict__ b1, const float* __restrict__ b2,
                      const float* __restrict__ b3, int nb, int n)
{
  int i = blockIdx.x * blockDim.x + threadIdx.x;
  if (i >= n) return;
  int d = i & 63;
  float bs = b0[d] + b1[d];
  if (nb == 4) bs += b2[d] + b3[d];
  float v = x[i] + bs;
  x[i] = v >= 0.f ? v : 0.01f * v;
}

__global__ void k_final(const float* __restrict__ x0, const float* __restrict__ x1,
                        const float* __restrict__ x2, float* __restrict__ out, int n)
{
  int i = blockIdx.x * blockDim.x + threadIdx.x;
  if (i < n) out[i] = (x0[i] + x1[i] + x2[i]) * (1.f / 3.f);
}

extern "C" void kernel_launch(void* const* d_in, const int* in_sizes, int n_in,
                              void* d_out, int out_size, void* d_ws, size_t ws_size,
                              hipStream_t stream)
{
  static const int ECNT[8] = {1000000, 1000000, 500000, 500000, 100000, 100000, 500000, 500000};
  static const int ESRC[8] = {0, 1, 0, 0, 1, 2, 0, 2};   // 0=user 1=article 2=category
  static const int EDST[8] = {1, 0, 0, 0, 2, 1, 2, 0};
  const int NSZ[3] = {kNUser, kNArt, kNCat};

  const float* x0[3] = {(const float*)d_in[0], (const float*)d_in[1], (const float*)d_in[2]};
  const float* Wsrc = (const float*)d_in[3];
  const float* Wdst = (const float*)d_in[4];
  const float* attS = (const float*)d_in[5];
  const float* attD = (const float*)d_in[6];
  const float* bias = (const float*)d_in[7];
  const int* ei[8];
  for (int t = 0; t < 8; ++t) ei[t] = (const int*)d_in[8 + t];

  float* ws = (float*)d_ws;
  float* xb[2][3];
  xb[0][0] = ws;           xb[0][1] = ws + SZ_U;      xb[0][2] = ws + SZ_U + SZ_A;
  float* w2 = ws + SZ_X;
  xb[1][0] = w2;           xb[1][1] = w2 + SZ_U;      xb[1][2] = w2 + SZ_U + SZ_A;
  float* hs  = ws + 2 * SZ_X;
  float* a_s = hs + SZ_U;
  float* a_d = a_s + 4 * (size_t)kNUser;
  int*   mmx = (int*)(a_d + 4 * (size_t)kNUser);
  float* den = (float*)mmx + 4 * (size_t)kNUser;
  float* vd  = den + 4 * (size_t)kNUser;

  const float* xcur[3] = {x0[0], x0[1], x0[2]};
  for (int l = 0; l < 2; ++l) {
    hipMemsetAsync(xb[l][0], 0, SZ_X * sizeof(float), stream);  // xb[l] is contiguous
    for (int t = 0; t < 8; ++t) {
      int s = ESRC[t], d = EDST[t];
      int Ns = NSZ[s], Nd = NSZ[d], E = ECNT[t];
      const float* Ws = Wsrc + (size_t)(l * 8 + t) * 4096;
      const float* Wd = Wdst + (size_t)(l * 8 + t) * 4096;
      const float* aS = attS + (size_t)(l * 8 + t) * 64;
      const float* aD = attD + (size_t)(l * 8 + t) * 64;
      k_vd<<<1, 256, 0, stream>>>(Wd, aD, vd);
      k_transform<<<(Ns + 63) / 64, 256, 0, stream>>>(xcur[s], Ws, aS, hs, a_s, Ns);
      k_ad<<<(Nd + 255) / 256, 256, 0, stream>>>(xcur[d], vd, a_d, Nd);
      k_init<<<(Nd * 4 + 255) / 256, 256, 0, stream>>>(mmx, den, Nd * 4);
      k_emax<<<(E + 255) / 256, 256, 0, stream>>>(ei[t], a_s, a_d, mmx, E);
      k_esum<<<(E + 255) / 256, 256, 0, stream>>>(ei[t], a_s, a_d, mmx, den, E);
      k_eagg<<<E / 4, 256, 0, stream>>>(ei[t], a_s, a_d, mmx, den, hs, xb[l][d], E);
    }
    const float* bl = bias + (size_t)l * 8 * 64;
    // dst lists: user {1,2,3,7}, article {0,5}, category {4,6}
    k_act<<<((int)SZ_U + 255) / 256, 256, 0, stream>>>(xb[l][0], bl + 64, bl + 128, bl + 192, bl + 448, 4, (int)SZ_U);
    k_act<<<((int)SZ_A + 255) / 256, 256, 0, stream>>>(xb[l][1], bl + 0,  bl + 320, bl, bl, 2, (int)SZ_A);
    k_act<<<((int)SZ_C + 255) / 256, 256, 0, stream>>>(xb[l][2], bl + 256, bl + 384, bl, bl, 2, (int)SZ_C);
    xcur[0] = xb[l][0]; xcur[1] = xb[l][1]; xcur[2] = xb[l][2];
  }
  k_final<<<((int)SZ_U + 255) / 256, 256, 0, stream>>>(x0[0], xb[0][0], xb[1][0], (float*)d_out, (int)SZ_U);
  k_final<<<((int)SZ_A + 255) / 256, 256, 0, stream>>>(x0[1], xb[0][1], xb[1][1], (float*)d_out + SZ_U, (int)SZ_A);
}

// Round 2
// 4335.446 us; speedup vs baseline: 2.1031x; 2.1031x over previous
//
#include <hip/hip_runtime.h>
#include <hip/hip_bf16.h>

// MAHGN: 2-layer hetero GAT, fp32.
// Round 2: CSR (dst-sorted) built once per launch; edge phase = single
// gather pass with online softmax (no global atomics in the hot loop).

static constexpr int kNUser = 200000;
static constexpr int kNArt  = 100000;
static constexpr int kNCat  = 500;
static constexpr size_t SZ_U = (size_t)kNUser * 64;
static constexpr size_t SZ_A = (size_t)kNArt * 64;
static constexpr size_t SZ_C = (size_t)kNCat * 64;
static constexpr size_t SZ_X = SZ_U + SZ_A + SZ_C;

// ---------------- dense transforms ----------------

// vd[k][h] = sum_c Wd[k][h*16+c] * att[h][c]  (folds hd into a 64x4 GEMV)
__global__ void k_vd(const float* __restrict__ Wd, const float* __restrict__ att,
                     float* __restrict__ vd) {
  int tid = threadIdx.x;          // 256 = 64 k * 4 h
  int k = tid >> 2, h = tid & 3;
  float s = 0.f;
  #pragma unroll
  for (int c = 0; c < 16; ++c) s += Wd[k * 64 + h * 16 + c] * att[h * 16 + c];
  vd[k * 4 + h] = s;
}

__device__ __forceinline__ void hs_as_write(float acc, float sAv, int tx, int row, int Ns,
                                            float* __restrict__ hs, float* __restrict__ a_s) {
  if (row < Ns) hs[(size_t)row * 64 + tx] = acc;
  float t = acc * sAv;
  t += __shfl_xor(t, 8, 64);
  t += __shfl_xor(t, 4, 64);
  t += __shfl_xor(t, 2, 64);
  t += __shfl_xor(t, 1, 64);
  if ((tx & 15) == 0 && row < Ns) a_s[row * 4 + (tx >> 4)] = t;
}

// hs = x @ W (64x64) + fused a_s. One wave computes 4 rows at a time.
__global__ __launch_bounds__(256) void k_transform(const float* __restrict__ x,
    const float* __restrict__ W, const float* __restrict__ att,
    float* __restrict__ hs, float* __restrict__ a_s, int Ns)
{
  __shared__ float sW[4096];
  __shared__ float sA[64];
  int tid = threadIdx.x;
  #pragma unroll
  for (int i = 0; i < 16; ++i) sW[tid + 256 * i] = W[tid + 256 * i];
  if (tid < 64) sA[tid] = att[tid];
  __syncthreads();
  int tx = tid & 63, wy = tid >> 6;
  float sAv = sA[tx];
  int base = blockIdx.x * 64 + wy * 16;
  #pragma unroll 1
  for (int it = 0; it < 4; ++it) {
    int r0 = base + it * 4;
    float xv0 = (r0 + 0 < Ns) ? x[(size_t)(r0 + 0) * 64 + tx] : 0.f;
    float xv1 = (r0 + 1 < Ns) ? x[(size_t)(r0 + 1) * 64 + tx] : 0.f;
    float xv2 = (r0 + 2 < Ns) ? x[(size_t)(r0 + 2) * 64 + tx] : 0.f;
    float xv3 = (r0 + 3 < Ns) ? x[(size_t)(r0 + 3) * 64 + tx] : 0.f;
    float a0 = 0.f, a1 = 0.f, a2 = 0.f, a3 = 0.f;
    #pragma unroll
    for (int k = 0; k < 64; ++k) {
      float w = sW[k * 64 + tx];
      a0 += __shfl(xv0, k, 64) * w;
      a1 += __shfl(xv1, k, 64) * w;
      a2 += __shfl(xv2, k, 64) * w;
      a3 += __shfl(xv3, k, 64) * w;
    }
    hs_as_write(a0, sAv, tx, r0 + 0, Ns, hs, a_s);
    hs_as_write(a1, sAv, tx, r0 + 1, Ns, hs, a_s);
    hs_as_write(a2, sAv, tx, r0 + 2, Ns, hs, a_s);
    hs_as_write(a3, sAv, tx, r0 + 3, Ns, hs, a_s);
  }
}

// a_d = x_d @ vd (64x4 GEMV)
__global__ __launch_bounds__(256) void k_ad(const float* __restrict__ x,
    const float* __restrict__ vd, float* __restrict__ a_d, int Nd)
{
  __shared__ float sV[256];
  int tid = threadIdx.x;
  sV[tid] = vd[tid];
  __syncthreads();
  int n = blockIdx.x * 256 + tid;
  if (n >= Nd) return;
  const float4* x4 = (const float4*)(x + (size_t)n * 64);
  float a0 = 0.f, a1 = 0.f, a2 = 0.f, a3 = 0.f;
  #pragma unroll
  for (int k4 = 0; k4 < 16; ++k4) {
    float4 xv = x4[k4];
    const float* f = &xv.x;
    #pragma unroll
    for (int j = 0; j < 4; ++j) {
      int k = k4 * 4 + j;
      float xk = f[j];
      a0 += xk * sV[k * 4 + 0];
      a1 += xk * sV[k * 4 + 1];
      a2 += xk * sV[k * 4 + 2];
      a3 += xk * sV[k * 4 + 3];
    }
  }
  *(float4*)(a_d + (size_t)n * 4) = make_float4(a0, a1, a2, a3);
}

// ---------------- CSR build ----------------

__global__ void k_hist(const int* __restrict__ col, int* __restrict__ deg, int E) {
  int i = blockIdx.x * blockDim.x + threadIdx.x;
  if (i < E) atomicAdd(&deg[col[i]], 1);
}

// small-Nd (<=512) variant: LDS counters, grid-stride
__global__ __launch_bounds__(256) void k_histS(const int* __restrict__ col,
    int* __restrict__ deg, int E, int Nd)
{
  __shared__ int cnt[512];
  for (int i = threadIdx.x; i < Nd; i += 256) cnt[i] = 0;
  __syncthreads();
  for (int i = blockIdx.x * 256 + threadIdx.x; i < E; i += gridDim.x * 256)
    atomicAdd(&cnt[col[i]], 1);
  __syncthreads();
  for (int i = threadIdx.x; i < Nd; i += 256) {
    int c = cnt[i];
    if (c) atomicAdd(&deg[i], c);
  }
}

__global__ void k_scan1(const int* __restrict__ deg, int* __restrict__ bsum, int n) {
  __shared__ int tmp[256];
  int i = blockIdx.x * 256 + threadIdx.x;
  tmp[threadIdx.x] = (i < n) ? deg[i] : 0;
  __syncthreads();
  for (int off = 128; off > 0; off >>= 1) {
    if (threadIdx.x < off) tmp[threadIdx.x] += tmp[threadIdx.x + off];
    __syncthreads();
  }
  if (threadIdx.x == 0) bsum[blockIdx.x] = tmp[0];
}

__global__ void k_scan2(int* __restrict__ bsum, int nb) {
  __shared__ int tmp[1024];
  int v = (threadIdx.x < nb) ? bsum[threadIdx.x] : 0;
  tmp[threadIdx.x] = v;
  __syncthreads();
  for (int off = 1; off < 1024; off <<= 1) {
    int t = (threadIdx.x >= off) ? tmp[threadIdx.x - off] : 0;
    __syncthreads();
    tmp[threadIdx.x] += t;
    __syncthreads();
  }
  if (threadIdx.x < nb) bsum[threadIdx.x] = tmp[threadIdx.x] - v;  // exclusive
}

__global__ void k_scan3(const int* __restrict__ deg, const int* __restrict__ bsum,
                        int* __restrict__ rowptr, int* __restrict__ cursor, int n)
{
  __shared__ int tmp[256];
  int i = blockIdx.x * 256 + threadIdx.x;
  int v = (i < n) ? deg[i] : 0;
  tmp[threadIdx.x] = v;
  __syncthreads();
  for (int off = 1; off < 256; off <<= 1) {
    int t = (threadIdx.x >= off) ? tmp[threadIdx.x - off] : 0;
    __syncthreads();
    tmp[threadIdx.x] += t;
    __syncthreads();
  }
  int excl = bsum[blockIdx.x] + tmp[threadIdx.x] - v;
  if (i < n) { rowptr[i] = excl; cursor[i] = excl; }
  if (i == n - 1) rowptr[n] = excl + v;
}

__global__ void k_scat(const int* __restrict__ row, const int* __restrict__ col,
                       int* __restrict__ cursor, int* __restrict__ rows, int E)
{
  int i = blockIdx.x * blockDim.x + threadIdx.x;
  if (i < E) {
    int p = atomicAdd(&cursor[col[i]], 1);
    rows[p] = row[i];
  }
}

// ---------------- gather (online softmax) ----------------

// 16 lanes per dst node; lane owns dims [lane*4, lane*4+4), head = lane>>2.
__global__ __launch_bounds__(256) void k_gather16(const int* __restrict__ rowptr,
    const int* __restrict__ rows, const float* __restrict__ a_s,
    const float* __restrict__ a_d, const float* __restrict__ hs,
    float* __restrict__ out, int Nd)
{
  int tid = threadIdx.x;
  int g = tid >> 4, lane = tid & 15, h = lane >> 2;
  int n = blockIdx.x * 16 + g;
  if (n >= Nd) return;
  float adh = a_d[(size_t)n * 4 + h];
  int start = rowptr[n], end = rowptr[n + 1];
  float m = -INFINITY, den = 0.f;
  float ax = 0.f, ay = 0.f, az = 0.f, aw = 0.f;
  for (int k = start; k < end; ++k) {
    int row = rows[k];
    float v = a_s[(size_t)row * 4 + h] + adh;
    v = v >= 0.f ? v : 0.2f * v;
    float mn = fmaxf(m, v);
    float c = __expf(m - mn);   // exp(-inf)=0 on first iter
    float p = __expf(v - mn);
    float4 hv = *(const float4*)(hs + (size_t)row * 64 + lane * 4);
    den = den * c + p;
    ax = ax * c + p * hv.x;
    ay = ay * c + p * hv.y;
    az = az * c + p * hv.z;
    aw = aw * c + p * hv.w;
    m = mn;
  }
  float inv = 1.f / (den + 1e-16f);
  float4* op = (float4*)(out + (size_t)n * 64) + lane;
  float4 prev = *op;                 // accumulate across edge types (HeteroConv sum)
  prev.x += ax * inv; prev.y += ay * inv; prev.z += az * inv; prev.w += aw * inv;
  *op = prev;
}

// workgroup per dst node (category dsts: Nd=500, deg 200..1000).
// 16 subgroups of 16 lanes, online-softmax partials merged in LDS.
__global__ __launch_bounds__(256) void k_gatherB(const int* __restrict__ rowptr,
    const int* __restrict__ rows, const float* __restrict__ a_s,
    const float* __restrict__ a_d, const float* __restrict__ hs,
    float* __restrict__ out)
{
  __shared__ float sm[64], sden[64], sacc[1024];
  int n = blockIdx.x;
  int tid = threadIdx.x;
  int sg = tid >> 4, lane = tid & 15, h = lane >> 2;
  float adh = a_d[(size_t)n * 4 + h];
  int start = rowptr[n], end = rowptr[n + 1];
  float m = -INFINITY, den = 0.f;
  float ax = 0.f, ay = 0.f, az = 0.f, aw = 0.f;
  for (int k = start + sg; k < end; k += 16) {
    int row = rows[k];
    float v = a_s[(size_t)row * 4 + h] + adh;
    v = v >= 0.f ? v : 0.2f * v;
    float mn = fmaxf(m, v);
    float c = __expf(m - mn);
    float p = __expf(v - mn);
    float4 hv = *(const float4*)(hs + (size_t)row * 64 + lane * 4);
    den = den * c + p;
    ax = ax * c + p * hv.x;
    ay = ay * c + p * hv.y;
    az = az * c + p * hv.z;
    aw = aw * c + p * hv.w;
    m = mn;
  }
  sacc[sg * 64 + lane * 4 + 0] = ax;
  sacc[sg * 64 + lane * 4 + 1] = ay;
  sacc[sg * 64 + lane * 4 + 2] = az;
  sacc[sg * 64 + lane * 4 + 3] = aw;
  if ((lane & 3) == 0) { sm[sg * 4 + h] = m; sden[sg * 4 + h] = den; }
  __syncthreads();
  if (tid < 64) {
    int hh = tid >> 4;
    float M = -INFINITY;
    #pragma unroll
    for (int g2 = 0; g2 < 16; ++g2) M = fmaxf(M, sm[g2 * 4 + hh]);
    if (M == -INFINITY) M = 0.f;
    float D = 0.f, A = 0.f;
    #pragma unroll
    for (int g2 = 0; g2 < 16; ++g2) {
      float mv = sm[g2 * 4 + hh];
      float c = (mv == -INFINITY) ? 0.f : __expf(mv - M);
      D += sden[g2 * 4 + hh] * c;
      A += sacc[g2 * 64 + tid] * c;
    }
    out[(size_t)n * 64 + tid] += A / (D + 1e-16f);
  }
}

// ---------------- epilogue ----------------

__global__ void k_act(float* __restrict__ x, const float* __restrict__ b0,
                      const float* __restrict__ b1, const float* __restrict__ b2,
                      const float* __restrict__ b3, int nb, int n)
{
  int i = blockIdx.x * blockDim.x + threadIdx.x;
  if (i >= n) return;
  int d = i & 63;
  float bs = b0[d] + b1[d];
  if (nb == 4) bs += b2[d] + b3[d];
  float v = x[i] + bs;
  x[i] = v >= 0.f ? v : 0.01f * v;
}

__global__ void k_final(const float* __restrict__ x0, const float* __restrict__ x1,
                        const float* __restrict__ x2, float* __restrict__ out, int n)
{
  int i = blockIdx.x * blockDim.x + threadIdx.x;
  if (i < n) out[i] = (x0[i] + x1[i] + x2[i]) * (1.f / 3.f);
}

// ---------------- launch ----------------

extern "C" void kernel_launch(void* const* d_in, const int* in_sizes, int n_in,
                              void* d_out, int out_size, void* d_ws, size_t ws_size,
                              hipStream_t stream)
{
  static const int ECNT[8] = {1000000, 1000000, 500000, 500000, 100000, 100000, 500000, 500000};
  static const int ESRC[8] = {0, 1, 0, 0, 1, 2, 0, 2};   // 0=user 1=article 2=category
  static const int EDST[8] = {1, 0, 0, 0, 2, 1, 2, 0};
  const int NSZ[3] = {kNUser, kNArt, kNCat};

  const float* x0[3] = {(const float*)d_in[0], (const float*)d_in[1], (const float*)d_in[2]};
  const float* Wsrc = (const float*)d_in[3];
  const float* Wdst = (const float*)d_in[4];
  const float* attS = (const float*)d_in[5];
  const float* attD = (const float*)d_in[6];
  const float* bias = (const float*)d_in[7];
  const int* ei[8];
  for (int t = 0; t < 8; ++t) ei[t] = (const int*)d_in[8 + t];

  float* ws = (float*)d_ws;
  size_t off = 0;
  auto alloc = [&](size_t nelem) { float* p = ws + off; off += nelem; return p; };
  float* xb0 = alloc(SZ_X);
  float* xb1 = alloc(SZ_X);
  float* hs  = alloc((size_t)kNUser * 64);      // max Ns*64
  float* a_s = alloc((size_t)kNUser * 4);
  float* a_d = alloc((size_t)kNUser * 4);
  float* vd  = alloc(256);
  int* rowptrA = (int*)alloc(1001008);           // sum(Nd+1) over types
  int* rowsA   = (int*)alloc(4200000);           // sum(E)
  int* cursor  = (int*)alloc(200001);
  int* deg     = (int*)alloc(200000);
  int* bsum    = (int*)alloc(1024);

  int* rowptr_t[8]; int* rows_t[8];
  {
    size_t ro = 0, eo = 0;
    for (int t = 0; t < 8; ++t) {
      int Nd = NSZ[EDST[t]];
      rowptr_t[t] = rowptrA + ro; ro += (size_t)Nd + 1;
      rows_t[t]   = rowsA + eo;   eo += (size_t)ECNT[t];
    }
  }

  // ---- CSR build (edges identical across layers) ----
  for (int t = 0; t < 8; ++t) {
    int Nd = NSZ[EDST[t]], E = ECNT[t];
    const int* row = ei[t];
    const int* col = ei[t] + E;
    hipMemsetAsync(deg, 0, (size_t)Nd * sizeof(int), stream);
    if (Nd <= 512) k_histS<<<256, 256, 0, stream>>>(col, deg, E, Nd);
    else           k_hist<<<(E + 255) / 256, 256, 0, stream>>>(col, deg, E);
    int nb = (Nd + 255) / 256;
    k_scan1<<<nb, 256, 0, stream>>>(deg, bsum, Nd);
    k_scan2<<<1, 1024, 0, stream>>>(bsum, nb);
    k_scan3<<<nb, 256, 0, stream>>>(deg, bsum, rowptr_t[t], cursor, Nd);
    k_scat<<<(E + 255) / 256, 256, 0, stream>>>(row, col, cursor, rows_t[t], E);
  }

  float* xb[2][3] = {{xb0, xb0 + SZ_U, xb0 + SZ_U + SZ_A},
                     {xb1, xb1 + SZ_U, xb1 + SZ_U + SZ_A}};
  const float* xcur[3] = {x0[0], x0[1], x0[2]};
  for (int l = 0; l < 2; ++l) {
    hipMemsetAsync(xb[l][0], 0, SZ_X * sizeof(float), stream);  // contiguous per layer
    for (int t = 0; t < 8; ++t) {
      int s = ESRC[t], d = EDST[t];
      int Ns = NSZ[s], Nd = NSZ[d];
      const float* Ws = Wsrc + (size_t)(l * 8 + t) * 4096;
      const float* Wd = Wdst + (size_t)(l * 8 + t) * 4096;
      const float* aS = attS + (size_t)(l * 8 + t) * 64;
      const float* aD = attD + (size_t)(l * 8 + t) * 64;
      k_vd<<<1, 256, 0, stream>>>(Wd, aD, vd);
      k_transform<<<(Ns + 63) / 64, 256, 0, stream>>>(xcur[s], Ws, aS, hs, a_s, Ns);
      k_ad<<<(Nd + 255) / 256, 256, 0, stream>>>(xcur[d], vd, a_d, Nd);
      if (Nd <= 512)
        k_gatherB<<<Nd, 256, 0, stream>>>(rowptr_t[t], rows_t[t], a_s, a_d, hs, xb[l][d]);
      else
        k_gather16<<<(Nd + 15) / 16, 256, 0, stream>>>(rowptr_t[t], rows_t[t], a_s, a_d, hs, xb[l][d], Nd);
    }
    const float* bl = bias + (size_t)l * 8 * 64;
    // dst lists: user {1,2,3,7}, article {0,5}, category {4,6}
    k_act<<<((int)SZ_U + 255) / 256, 256, 0, stream>>>(xb[l][0], bl + 64, bl + 128, bl + 192, bl + 448, 4, (int)SZ_U);
    k_act<<<((int)SZ_A + 255) / 256, 256, 0, stream>>>(xb[l][1], bl + 0,  bl + 320, bl, bl, 2, (int)SZ_A);
    k_act<<<((int)SZ_C + 255) / 256, 256, 0, stream>>>(xb[l][2], bl + 256, bl + 384, bl, bl, 2, (int)SZ_C);
    xcur[0] = xb[l][0]; xcur[1] = xb[l][1]; xcur[2] = xb[l][2];
  }
  k_final<<<((int)SZ_U + 255) / 256, 256, 0, stream>>>(x0[0], xb[0][0], xb[1][0], (float*)d_out, (int)SZ_U);
  k_final<<<((int)SZ_A + 255) / 256, 256, 0, stream>>>(x0[1], xb[0][1], xb[1][1], (float*)d_out + SZ_U, (int)SZ_A);
}

// Round 3
// 2184.072 us; speedup vs baseline: 4.1748x; 1.9850x over previous
//
#include <hip/hip_runtime.h>
#include <hip/hip_bf16.h>

// MAHGN: 2-layer hetero GAT, fp32.
// Round 3: transform rewritten as LDS-tiled outer-product GEMM (no shuffles
// in hot loop -> VALU-bound instead of LDS-pipe-bound). k_vd folded into k_ad.

static constexpr int kNUser = 200000;
static constexpr int kNArt  = 100000;
static constexpr int kNCat  = 500;
static constexpr size_t SZ_U = (size_t)kNUser * 64;
static constexpr size_t SZ_A = (size_t)kNArt * 64;
static constexpr size_t SZ_C = (size_t)kNCat * 64;
static constexpr size_t SZ_X = SZ_U + SZ_A + SZ_C;

// ---------------- dense transforms ----------------

// hs = x @ W (64x64) + fused a_s.
// 256 threads: tile 64 rows x 64 cols, thread = 4x4 register tile.
// sXt is k-major transposed with pad 68 (16B-aligned b128 rows, 2-way banks).
__global__ __launch_bounds__(256, 4) void k_transform(const float* __restrict__ x,
    const float* __restrict__ W, const float* __restrict__ att,
    float* __restrict__ hs, float* __restrict__ a_s, int Ns)
{
  __shared__ float sXt[64 * 68];
  __shared__ float sW[64 * 64];
  __shared__ float sAtt[64];
  int tid = threadIdx.x;
  int r0 = blockIdx.x * 64;

  // stage W: layout W[k*64+c] == sW[k][c]
  {
    const float4* w4 = (const float4*)W;
    float4* s4 = (float4*)sW;
    #pragma unroll
    for (int i = 0; i < 4; ++i) s4[tid + 256 * i] = w4[tid + 256 * i];
  }
  if (tid < 64) sAtt[tid] = att[tid];
  // stage X transposed: lane (r = tid>>4, kq = tid&15) reads x[row][kq*4..+3]
  {
    int r = tid >> 4, kq = tid & 15;
    #pragma unroll
    for (int rg = 0; rg < 4; ++rg) {
      int row = r0 + rg * 16 + r;
      float4 xv = make_float4(0.f, 0.f, 0.f, 0.f);
      if (row < Ns) xv = *(const float4*)(x + (size_t)row * 64 + kq * 4);
      sXt[(kq * 4 + 0) * 68 + rg * 16 + r] = xv.x;
      sXt[(kq * 4 + 1) * 68 + rg * 16 + r] = xv.y;
      sXt[(kq * 4 + 2) * 68 + rg * 16 + r] = xv.z;
      sXt[(kq * 4 + 3) * 68 + rg * 16 + r] = xv.w;
    }
  }
  __syncthreads();

  int c4 = tid & 15, r4 = tid >> 4;   // cols c4*4.., rows r4*4..
  float acc[4][4];
  #pragma unroll
  for (int i = 0; i < 4; ++i)
    #pragma unroll
    for (int j = 0; j < 4; ++j) acc[i][j] = 0.f;

  #pragma unroll 16
  for (int k = 0; k < 64; ++k) {
    float4 xv = *(const float4*)&sXt[k * 68 + r4 * 4];
    float4 wv = *(const float4*)&sW[k * 64 + c4 * 4];
    const float* xf = &xv.x;
    const float* wf = &wv.x;
    #pragma unroll
    for (int i = 0; i < 4; ++i)
      #pragma unroll
      for (int j = 0; j < 4; ++j) acc[i][j] += xf[i] * wf[j];
  }

  // epilogue: store hs + fused a_s (head h = c4>>2; cols c4*4+j within head)
  float attv[4];
  #pragma unroll
  for (int j = 0; j < 4; ++j) attv[j] = sAtt[c4 * 4 + j];
  int h = c4 >> 2;
  #pragma unroll
  for (int i = 0; i < 4; ++i) {
    int row = r0 + r4 * 4 + i;
    bool ok = row < Ns;
    if (ok) *(float4*)(hs + (size_t)row * 64 + c4 * 4) =
        make_float4(acc[i][0], acc[i][1], acc[i][2], acc[i][3]);
    float p = acc[i][0] * attv[0] + acc[i][1] * attv[1] +
              acc[i][2] * attv[2] + acc[i][3] * attv[3];
    p += __shfl_xor(p, 1, 64);
    p += __shfl_xor(p, 2, 64);
    if ((c4 & 3) == 0 && ok) a_s[(size_t)row * 4 + h] = p;
  }
}

// a_d = x_d @ vd (64x4 GEMV); vd[k][h] = sum_c Wd[k][h*16+c]*att[h][c]
// computed redundantly per block (cheap) -- removes the 1-block k_vd dispatches.
__global__ __launch_bounds__(256) void k_ad(const float* __restrict__ x,
    const float* __restrict__ Wd, const float* __restrict__ att,
    float* __restrict__ a_d, int Nd)
{
  __shared__ float sV[256];
  int tid = threadIdx.x;
  {
    int k = tid >> 2, h = tid & 3;
    float s = 0.f;
    #pragma unroll
    for (int c = 0; c < 16; ++c) s += Wd[k * 64 + h * 16 + c] * att[h * 16 + c];
    sV[k * 4 + h] = s;
  }
  __syncthreads();
  int n = blockIdx.x * 256 + tid;
  if (n >= Nd) return;
  const float4* x4 = (const float4*)(x + (size_t)n * 64);
  float a0 = 0.f, a1 = 0.f, a2 = 0.f, a3 = 0.f;
  #pragma unroll
  for (int k4 = 0; k4 < 16; ++k4) {
    float4 xv = x4[k4];
    const float* f = &xv.x;
    #pragma unroll
    for (int j = 0; j < 4; ++j) {
      int k = k4 * 4 + j;
      float xk = f[j];
      a0 += xk * sV[k * 4 + 0];
      a1 += xk * sV[k * 4 + 1];
      a2 += xk * sV[k * 4 + 2];
      a3 += xk * sV[k * 4 + 3];
    }
  }
  *(float4*)(a_d + (size_t)n * 4) = make_float4(a0, a1, a2, a3);
}

// ---------------- CSR build ----------------

__global__ void k_hist(const int* __restrict__ col, int* __restrict__ deg, int E) {
  int i = blockIdx.x * blockDim.x + threadIdx.x;
  if (i < E) atomicAdd(&deg[col[i]], 1);
}

__global__ __launch_bounds__(256) void k_histS(const int* __restrict__ col,
    int* __restrict__ deg, int E, int Nd)
{
  __shared__ int cnt[512];
  for (int i = threadIdx.x; i < Nd; i += 256) cnt[i] = 0;
  __syncthreads();
  for (int i = blockIdx.x * 256 + threadIdx.x; i < E; i += gridDim.x * 256)
    atomicAdd(&cnt[col[i]], 1);
  __syncthreads();
  for (int i = threadIdx.x; i < Nd; i += 256) {
    int c = cnt[i];
    if (c) atomicAdd(&deg[i], c);
  }
}

__global__ void k_scan1(const int* __restrict__ deg, int* __restrict__ bsum, int n) {
  __shared__ int tmp[256];
  int i = blockIdx.x * 256 + threadIdx.x;
  tmp[threadIdx.x] = (i < n) ? deg[i] : 0;
  __syncthreads();
  for (int off = 128; off > 0; off >>= 1) {
    if (threadIdx.x < off) tmp[threadIdx.x] += tmp[threadIdx.x + off];
    __syncthreads();
  }
  if (threadIdx.x == 0) bsum[blockIdx.x] = tmp[0];
}

__global__ void k_scan2(int* __restrict__ bsum, int nb) {
  __shared__ int tmp[1024];
  int v = (threadIdx.x < nb) ? bsum[threadIdx.x] : 0;
  tmp[threadIdx.x] = v;
  __syncthreads();
  for (int off = 1; off < 1024; off <<= 1) {
    int t = (threadIdx.x >= off) ? tmp[threadIdx.x - off] : 0;
    __syncthreads();
    tmp[threadIdx.x] += t;
    __syncthreads();
  }
  if (threadIdx.x < nb) bsum[threadIdx.x] = tmp[threadIdx.x] - v;  // exclusive
}

__global__ void k_scan3(const int* __restrict__ deg, const int* __restrict__ bsum,
                        int* __restrict__ rowptr, int* __restrict__ cursor, int n)
{
  __shared__ int tmp[256];
  int i = blockIdx.x * 256 + threadIdx.x;
  int v = (i < n) ? deg[i] : 0;
  tmp[threadIdx.x] = v;
  __syncthreads();
  for (int off = 1; off < 256; off <<= 1) {
    int t = (threadIdx.x >= off) ? tmp[threadIdx.x - off] : 0;
    __syncthreads();
    tmp[threadIdx.x] += t;
    __syncthreads();
  }
  int excl = bsum[blockIdx.x] + tmp[threadIdx.x] - v;
  if (i < n) { rowptr[i] = excl; cursor[i] = excl; }
  if (i == n - 1) rowptr[n] = excl + v;
}

__global__ void k_scat(const int* __restrict__ row, const int* __restrict__ col,
                       int* __restrict__ cursor, int* __restrict__ rows, int E)
{
  int i = blockIdx.x * blockDim.x + threadIdx.x;
  if (i < E) {
    int p = atomicAdd(&cursor[col[i]], 1);
    rows[p] = row[i];
  }
}

// ---------------- gather (online softmax) ----------------

__global__ __launch_bounds__(256) void k_gather16(const int* __restrict__ rowptr,
    const int* __restrict__ rows, const float* __restrict__ a_s,
    const float* __restrict__ a_d, const float* __restrict__ hs,
    float* __restrict__ out, int Nd)
{
  int tid = threadIdx.x;
  int g = tid >> 4, lane = tid & 15, h = lane >> 2;
  int n = blockIdx.x * 16 + g;
  if (n >= Nd) return;
  float adh = a_d[(size_t)n * 4 + h];
  int start = rowptr[n], end = rowptr[n + 1];
  float m = -INFINITY, den = 0.f;
  float ax = 0.f, ay = 0.f, az = 0.f, aw = 0.f;
  for (int k = start; k < end; ++k) {
    int row = rows[k];
    float v = a_s[(size_t)row * 4 + h] + adh;
    v = v >= 0.f ? v : 0.2f * v;
    float mn = fmaxf(m, v);
    float c = __expf(m - mn);
    float p = __expf(v - mn);
    float4 hv = *(const float4*)(hs + (size_t)row * 64 + lane * 4);
    den = den * c + p;
    ax = ax * c + p * hv.x;
    ay = ay * c + p * hv.y;
    az = az * c + p * hv.z;
    aw = aw * c + p * hv.w;
    m = mn;
  }
  float inv = 1.f / (den + 1e-16f);
  float4* op = (float4*)(out + (size_t)n * 64) + lane;
  float4 prev = *op;                 // accumulate across edge types
  prev.x += ax * inv; prev.y += ay * inv; prev.z += az * inv; prev.w += aw * inv;
  *op = prev;
}

__global__ __launch_bounds__(256) void k_gatherB(const int* __restrict__ rowptr,
    const int* __restrict__ rows, const float* __restrict__ a_s,
    const float* __restrict__ a_d, const float* __restrict__ hs,
    float* __restrict__ out)
{
  __shared__ float sm[64], sden[64], sacc[1024];
  int n = blockIdx.x;
  int tid = threadIdx.x;
  int sg = tid >> 4, lane = tid & 15, h = lane >> 2;
  float adh = a_d[(size_t)n * 4 + h];
  int start = rowptr[n], end = rowptr[n + 1];
  float m = -INFINITY, den = 0.f;
  float ax = 0.f, ay = 0.f, az = 0.f, aw = 0.f;
  for (int k = start + sg; k < end; k += 16) {
    int row = rows[k];
    float v = a_s[(size_t)row * 4 + h] + adh;
    v = v >= 0.f ? v : 0.2f * v;
    float mn = fmaxf(m, v);
    float c = __expf(m - mn);
    float p = __expf(v - mn);
    float4 hv = *(const float4*)(hs + (size_t)row * 64 + lane * 4);
    den = den * c + p;
    ax = ax * c + p * hv.x;
    ay = ay * c + p * hv.y;
    az = az * c + p * hv.z;
    aw = aw * c + p * hv.w;
    m = mn;
  }
  sacc[sg * 64 + lane * 4 + 0] = ax;
  sacc[sg * 64 + lane * 4 + 1] = ay;
  sacc[sg * 64 + lane * 4 + 2] = az;
  sacc[sg * 64 + lane * 4 + 3] = aw;
  if ((lane & 3) == 0) { sm[sg * 4 + h] = m; sden[sg * 4 + h] = den; }
  __syncthreads();
  if (tid < 64) {
    int hh = tid >> 4;
    float M = -INFINITY;
    #pragma unroll
    for (int g2 = 0; g2 < 16; ++g2) M = fmaxf(M, sm[g2 * 4 + hh]);
    if (M == -INFINITY) M = 0.f;
    float D = 0.f, A = 0.f;
    #pragma unroll
    for (int g2 = 0; g2 < 16; ++g2) {
      float mv = sm[g2 * 4 + hh];
      float c = (mv == -INFINITY) ? 0.f : __expf(mv - M);
      D += sden[g2 * 4 + hh] * c;
      A += sacc[g2 * 64 + tid] * c;
    }
    out[(size_t)n * 64 + tid] += A / (D + 1e-16f);
  }
}

// ---------------- epilogue ----------------

__global__ void k_act(float* __restrict__ x, const float* __restrict__ b0,
                      const float* __restrict__ b1, const float* __restrict__ b2,
                      const float* __restrict__ b3, int nb, int n)
{
  int i = blockIdx.x * blockDim.x + threadIdx.x;
  if (i >= n) return;
  int d = i & 63;
  float bs = b0[d] + b1[d];
  if (nb == 4) bs += b2[d] + b3[d];
  float v = x[i] + bs;
  x[i] = v >= 0.f ? v : 0.01f * v;
}

__global__ void k_final(const float* __restrict__ x0, const float* __restrict__ x1,
                        const float* __restrict__ x2, float* __restrict__ out, int n)
{
  int i = blockIdx.x * blockDim.x + threadIdx.x;
  if (i < n) out[i] = (x0[i] + x1[i] + x2[i]) * (1.f / 3.f);
}

// ---------------- launch ----------------

extern "C" void kernel_launch(void* const* d_in, const int* in_sizes, int n_in,
                              void* d_out, int out_size, void* d_ws, size_t ws_size,
                              hipStream_t stream)
{
  static const int ECNT[8] = {1000000, 1000000, 500000, 500000, 100000, 100000, 500000, 500000};
  static const int ESRC[8] = {0, 1, 0, 0, 1, 2, 0, 2};   // 0=user 1=article 2=category
  static const int EDST[8] = {1, 0, 0, 0, 2, 1, 2, 0};
  const int NSZ[3] = {kNUser, kNArt, kNCat};

  const float* x0[3] = {(const float*)d_in[0], (const float*)d_in[1], (const float*)d_in[2]};
  const float* Wsrc = (const float*)d_in[3];
  const float* Wdst = (const float*)d_in[4];
  const float* attS = (const float*)d_in[5];
  const float* attD = (const float*)d_in[6];
  const float* bias = (const float*)d_in[7];
  const int* ei[8];
  for (int t = 0; t < 8; ++t) ei[t] = (const int*)d_in[8 + t];

  float* ws = (float*)d_ws;
  size_t off = 0;
  auto alloc = [&](size_t nelem) { float* p = ws + off; off += nelem; return p; };
  float* xb0 = alloc(SZ_X);
  float* xb1 = alloc(SZ_X);
  float* hs  = alloc((size_t)kNUser * 64);
  float* a_s = alloc((size_t)kNUser * 4);
  float* a_d = alloc((size_t)kNUser * 4);
  int* rowptrA = (int*)alloc(1001008);
  int* rowsA   = (int*)alloc(4200000);
  int* cursor  = (int*)alloc(200001);
  int* deg     = (int*)alloc(200000);
  int* bsum    = (int*)alloc(1024);

  int* rowptr_t[8]; int* rows_t[8];
  {
    size_t ro = 0, eo = 0;
    for (int t = 0; t < 8; ++t) {
      int Nd = NSZ[EDST[t]];
      rowptr_t[t] = rowptrA + ro; ro += (size_t)Nd + 1;
      rows_t[t]   = rowsA + eo;   eo += (size_t)ECNT[t];
    }
  }

  // ---- CSR build (edges identical across layers) ----
  for (int t = 0; t < 8; ++t) {
    int Nd = NSZ[EDST[t]], E = ECNT[t];
    const int* row = ei[t];
    const int* col = ei[t] + E;
    hipMemsetAsync(deg, 0, (size_t)Nd * sizeof(int), stream);
    if (Nd <= 512) k_histS<<<256, 256, 0, stream>>>(col, deg, E, Nd);
    else           k_hist<<<(E + 255) / 256, 256, 0, stream>>>(col, deg, E);
    int nb = (Nd + 255) / 256;
    k_scan1<<<nb, 256, 0, stream>>>(deg, bsum, Nd);
    k_scan2<<<1, 1024, 0, stream>>>(bsum, nb);
    k_scan3<<<nb, 256, 0, stream>>>(deg, bsum, rowptr_t[t], cursor, Nd);
    k_scat<<<(E + 255) / 256, 256, 0, stream>>>(row, col, cursor, rows_t[t], E);
  }

  float* xb[2][3] = {{xb0, xb0 + SZ_U, xb0 + SZ_U + SZ_A},
                     {xb1, xb1 + SZ_U, xb1 + SZ_U + SZ_A}};
  const float* xcur[3] = {x0[0], x0[1], x0[2]};
  for (int l = 0; l < 2; ++l) {
    hipMemsetAsync(xb[l][0], 0, SZ_X * sizeof(float), stream);
    for (int t = 0; t < 8; ++t) {
      int s = ESRC[t], d = EDST[t];
      int Ns = NSZ[s], Nd = NSZ[d];
      const float* Ws = Wsrc + (size_t)(l * 8 + t) * 4096;
      const float* Wd = Wdst + (size_t)(l * 8 + t) * 4096;
      const float* aS = attS + (size_t)(l * 8 + t) * 64;
      const float* aD = attD + (size_t)(l * 8 + t) * 64;
      k_transform<<<(Ns + 63) / 64, 256, 0, stream>>>(xcur[s], Ws, aS, hs, a_s, Ns);
      k_ad<<<(Nd + 255) / 256, 256, 0, stream>>>(xcur[d], Wd, aD, a_d, Nd);
      if (Nd <= 512)
        k_gatherB<<<Nd, 256, 0, stream>>>(rowptr_t[t], rows_t[t], a_s, a_d, hs, xb[l][d]);
      else
        k_gather16<<<(Nd + 15) / 16, 256, 0, stream>>>(rowptr_t[t], rows_t[t], a_s, a_d, hs, xb[l][d], Nd);
    }
    const float* bl = bias + (size_t)l * 8 * 64;
    // dst lists: user {1,2,3,7}, article {0,5}, category {4,6}
    k_act<<<((int)SZ_U + 255) / 256, 256, 0, stream>>>(xb[l][0], bl + 64, bl + 128, bl + 192, bl + 448, 4, (int)SZ_U);
    k_act<<<((int)SZ_A + 255) / 256, 256, 0, stream>>>(xb[l][1], bl + 0,  bl + 320, bl, bl, 2, (int)SZ_A);
    k_act<<<((int)SZ_C + 255) / 256, 256, 0, stream>>>(xb[l][2], bl + 256, bl + 384, bl, bl, 2, (int)SZ_C);
    xcur[0] = xb[l][0]; xcur[1] = xb[l][1]; xcur[2] = xb[l][2];
  }
  k_final<<<((int)SZ_U + 255) / 256, 256, 0, stream>>>(x0[0], xb[0][0], xb[1][0], (float*)d_out, (int)SZ_U);
  k_final<<<((int)SZ_A + 255) / 256, 256, 0, stream>>>(x0[1], xb[0][1], xb[1][1], (float*)d_out + SZ_U, (int)SZ_A);
}